// Round 2
// baseline (2537.948 us; speedup 1.0000x reference)
//
#include <hip/hip_runtime.h>
#include <hip/hip_bf16.h>

#define N_NODES 100000
#define N_EDGES 1600000
#define D 128
#define N_LAYERS 4
#define N_GRAPHS 64
#define N_CLASS 10
#define BN_EPS 1e-5f

#define CHUNK 2048
#define NCHUNKS 49  // ceil(100000/2048)
#define POOL_ROWS 1024

// ---------------- utility: zero a u32 buffer ----------------
__global__ void zero_u32_kernel(unsigned int* __restrict__ p, int n) {
    int i = blockIdx.x * blockDim.x + threadIdx.x;
    if (i < n) p[i] = 0u;
}

// ---------------- CSR build ----------------
__global__ void hist_kernel(const int* __restrict__ dst, int* __restrict__ counts) {
    int stride = gridDim.x * blockDim.x;
    for (int e = blockIdx.x * blockDim.x + threadIdx.x; e < N_EDGES; e += stride)
        atomicAdd(&counts[dst[e]], 1);
}

__global__ void scan1_kernel(const int* __restrict__ counts, int* __restrict__ chunkSum) {
    __shared__ int red[4];
    int b = blockIdx.x, t = threadIdx.x;
    int base = b * CHUNK;
    int s = 0;
    for (int i = t; i < CHUNK; i += 256) {
        int g = base + i;
        s += (g < N_NODES) ? counts[g] : 0;
    }
    for (int off = 32; off > 0; off >>= 1) s += __shfl_down(s, off, 64);
    if ((t & 63) == 0) red[t >> 6] = s;
    __syncthreads();
    if (t == 0) chunkSum[b] = red[0] + red[1] + red[2] + red[3];
}

__global__ void scan2_kernel(const int* __restrict__ chunkSum, int* __restrict__ chunkOff,
                             int* __restrict__ rowptr) {
    if (threadIdx.x == 0) {
        int run = 0;
        for (int i = 0; i < NCHUNKS; ++i) { chunkOff[i] = run; run += chunkSum[i]; }
        rowptr[N_NODES] = run;
    }
}

__global__ void scan3_kernel(const int* __restrict__ counts, const int* __restrict__ chunkOff,
                             int* __restrict__ rowptr, int* __restrict__ cursor) {
    __shared__ int lds[256];
    int b = blockIdx.x, t = threadIdx.x;
    int base = b * CHUNK + t * 8;
    int v[8];
    int run = 0;
#pragma unroll
    for (int i = 0; i < 8; ++i) {
        int g = base + i;
        int c = (g < N_NODES) ? counts[g] : 0;
        v[i] = run; run += c;
    }
    lds[t] = run;
    __syncthreads();
    for (int off = 1; off < 256; off <<= 1) {
        int xv = (t >= off) ? lds[t - off] : 0;
        __syncthreads();
        lds[t] += xv;
        __syncthreads();
    }
    int tpre = lds[t] - run;  // exclusive prefix of thread totals
    int o0 = chunkOff[b];
#pragma unroll
    for (int i = 0; i < 8; ++i) {
        int g = base + i;
        if (g < N_NODES) { int val = o0 + tpre + v[i]; rowptr[g] = val; cursor[g] = val; }
    }
}

__global__ void fill_kernel(const int* __restrict__ src, const int* __restrict__ dst,
                            int* __restrict__ cursor, int* __restrict__ colidx) {
    int stride = gridDim.x * blockDim.x;
    for (int e = blockIdx.x * blockDim.x + threadIdx.x; e < N_EDGES; e += stride) {
        int d = dst[e];
        int p = atomicAdd(&cursor[d], 1);
        colidx[p] = src[e];
    }
}

// ---------------- standardization ----------------
__global__ void colstats_kernel(const float* __restrict__ x, float* __restrict__ stats) {
    // 128 threads/block, 256 rows/block; thread f owns feature f
    int f = threadIdx.x;
    int r0 = blockIdx.x * 256;
    float ps = 0.f, psq = 0.f;
    for (int i = 0; i < 256; ++i) {
        int r = r0 + i;
        if (r < N_NODES) {
            float v = x[(size_t)r * D + f];
            ps += v; psq += v * v;
        }
    }
    atomicAdd(&stats[f], ps);
    atomicAdd(&stats[D + f], psq);
}

__global__ void standardize_kernel(const float* __restrict__ x, const float* __restrict__ stats,
                                   float* __restrict__ h) {
    const float invN = 1.f / (float)N_NODES;
    int stride = gridDim.x * blockDim.x;
    const int total = N_NODES * (D / 4);
    for (int idx = blockIdx.x * blockDim.x + threadIdx.x; idx < total; idx += stride) {
        int f = (idx & 31) * 4;
        float4 v = ((const float4*)x)[idx];
        float4 o;
        {
            float mu = stats[f + 0] * invN;
            float sd = sqrtf(stats[D + f + 0] * invN - mu * mu);
            o.x = (v.x - mu) / sd;
        }
        {
            float mu = stats[f + 1] * invN;
            float sd = sqrtf(stats[D + f + 1] * invN - mu * mu);
            o.y = (v.y - mu) / sd;
        }
        {
            float mu = stats[f + 2] * invN;
            float sd = sqrtf(stats[D + f + 2] * invN - mu * mu);
            o.z = (v.z - mu) / sd;
        }
        {
            float mu = stats[f + 3] * invN;
            float sd = sqrtf(stats[D + f + 3] * invN - mu * mu);
            o.w = (v.w - mu) / sd;
        }
        ((float4*)h)[idx] = o;
    }
}

// ---------------- GIN aggregation: z0 = (1+eps)*h + sum_{in-edges} h[src] ----------------
__global__ void agg_kernel(const float* __restrict__ h, const int* __restrict__ rowptr,
                           const int* __restrict__ colidx, const float* __restrict__ eps, int l,
                           float* __restrict__ z0) {
    int node = blockIdx.x * 2 + (threadIdx.x >> 7);  // 2 nodes per 256-thread block
    int f = threadIdx.x & 127;
    float acc = (1.f + eps[l]) * h[(size_t)node * D + f];
    int e0 = rowptr[node], e1 = rowptr[node + 1];
    for (int e = e0; e < e1; ++e) {
        int s = colidx[e];
        acc += h[(size_t)s * D + f];
    }
    z0[(size_t)node * D + f] = acc;
}

// ---------------- fused MLP: z2 = relu(relu(z0@W1+b1)@W2+b2), + BN stat accumulation ------
__launch_bounds__(256, 2)
__global__ void mlp_kernel(const float* __restrict__ z0,
                           const float* __restrict__ W1, const float* __restrict__ b1,
                           const float* __restrict__ W2, const float* __restrict__ b2,
                           float* __restrict__ out, float* __restrict__ stats) {
    __shared__ float As[32][64];    // [k][m] transposed A tile
    __shared__ float Bs[32][128];   // [k][c] weight tile
    __shared__ float Z1[128][64];   // [k][m] intermediate (full K)
    __shared__ float Ssum[128];
    __shared__ float Ssq[128];

    int tid = threadIdx.x;
    int rb = blockIdx.x * 64;
    int tr = tid >> 5;     // 0..7
    int tc = tid & 31;     // 0..31
    int r0 = tr * 8;
    int c0 = tc * 4;

    if (tid < 128) { Ssum[tid] = 0.f; Ssq[tid] = 0.f; }

    float acc[8][4];
#pragma unroll
    for (int i = 0; i < 8; ++i)
#pragma unroll
        for (int j = 0; j < 4; ++j) acc[i][j] = 0.f;

    // ---- GEMM1: z1 = z0 @ W1 ----
    for (int k0 = 0; k0 < 128; k0 += 32) {
        // stage A tile (64 rows x 32 k), transposed into As[k][m]
#pragma unroll
        for (int i = 0; i < 2; ++i) {
            int slot = tid + i * 256;       // 0..511
            int m = slot >> 3;              // 0..63
            int kq = slot & 7;              // float4 group
            float4 v = make_float4(0.f, 0.f, 0.f, 0.f);
            int gr = rb + m;
            if (gr < N_NODES) v = *(const float4*)&z0[(size_t)gr * D + k0 + kq * 4];
            As[kq * 4 + 0][m] = v.x;
            As[kq * 4 + 1][m] = v.y;
            As[kq * 4 + 2][m] = v.z;
            As[kq * 4 + 3][m] = v.w;
        }
        // stage B tile (32 k x 128 c)
#pragma unroll
        for (int i = 0; i < 4; ++i) {
            int slot = tid + i * 256;       // 0..1023
            int k = slot >> 5;
            int cq = slot & 31;
            *(float4*)&Bs[k][cq * 4] = *(const float4*)&W1[(size_t)(k0 + k) * D + cq * 4];
        }
        __syncthreads();
#pragma unroll
        for (int k = 0; k < 32; ++k) {
            float a[8], bb[4];
            *(float4*)&a[0] = *(const float4*)&As[k][r0];
            *(float4*)&a[4] = *(const float4*)&As[k][r0 + 4];
            *(float4*)&bb[0] = *(const float4*)&Bs[k][c0];
#pragma unroll
            for (int i = 0; i < 8; ++i)
#pragma unroll
                for (int j = 0; j < 4; ++j) acc[i][j] = fmaf(a[i], bb[j], acc[i][j]);
        }
        __syncthreads();
    }

    // bias + relu -> Z1 (transposed [c][m])
    {
        float bias[4];
#pragma unroll
        for (int j = 0; j < 4; ++j) bias[j] = b1[c0 + j];
#pragma unroll
        for (int i = 0; i < 8; ++i)
#pragma unroll
            for (int j = 0; j < 4; ++j)
                Z1[c0 + j][r0 + i] = fmaxf(acc[i][j] + bias[j], 0.f);
    }
    __syncthreads();

    // ---- GEMM2: z2 = z1 @ W2 ----
    float acc2[8][4];
#pragma unroll
    for (int i = 0; i < 8; ++i)
#pragma unroll
        for (int j = 0; j < 4; ++j) acc2[i][j] = 0.f;

    for (int k0 = 0; k0 < 128; k0 += 32) {
#pragma unroll
        for (int i = 0; i < 4; ++i) {
            int slot = tid + i * 256;
            int k = slot >> 5;
            int cq = slot & 31;
            *(float4*)&Bs[k][cq * 4] = *(const float4*)&W2[(size_t)(k0 + k) * D + cq * 4];
        }
        __syncthreads();
#pragma unroll
        for (int k = 0; k < 32; ++k) {
            float a[8], bb[4];
            *(float4*)&a[0] = *(const float4*)&Z1[k0 + k][r0];
            *(float4*)&a[4] = *(const float4*)&Z1[k0 + k][r0 + 4];
            *(float4*)&bb[0] = *(const float4*)&Bs[k][c0];
#pragma unroll
            for (int i = 0; i < 8; ++i)
#pragma unroll
                for (int j = 0; j < 4; ++j) acc2[i][j] = fmaf(a[i], bb[j], acc2[i][j]);
        }
        __syncthreads();
    }

    // bias + relu + store + BN stats
    {
        float bias[4];
#pragma unroll
        for (int j = 0; j < 4; ++j) bias[j] = b2[c0 + j];
        float vz[8][4];
#pragma unroll
        for (int i = 0; i < 8; ++i)
#pragma unroll
            for (int j = 0; j < 4; ++j) vz[i][j] = fmaxf(acc2[i][j] + bias[j], 0.f);
#pragma unroll
        for (int i = 0; i < 8; ++i) {
            int gr = rb + r0 + i;
            if (gr < N_NODES) *(float4*)&out[(size_t)gr * D + c0] = *(float4*)&vz[i][0];
        }
#pragma unroll
        for (int j = 0; j < 4; ++j) {
            float ps = 0.f, psq = 0.f;
#pragma unroll
            for (int i = 0; i < 8; ++i) {
                int gr = rb + r0 + i;
                if (gr < N_NODES) { float v = vz[i][j]; ps += v; psq += v * v; }
            }
            atomicAdd(&Ssum[c0 + j], ps);
            atomicAdd(&Ssq[c0 + j], psq);
        }
    }
    __syncthreads();
    if (tid < 128) {
        atomicAdd(&stats[tid], Ssum[tid]);
        atomicAdd(&stats[D + tid], Ssq[tid]);
    }
}

// ---------------- BN (training-mode batch stats) + relu, in place ----------------
__global__ void bn_relu_kernel(float* __restrict__ h, const float* __restrict__ stats,
                               const float* __restrict__ gamma, const float* __restrict__ beta) {
    const float invN = 1.f / (float)N_NODES;
    int stride = gridDim.x * blockDim.x;
    const int total = N_NODES * (D / 4);
    for (int idx = blockIdx.x * blockDim.x + threadIdx.x; idx < total; idx += stride) {
        int f = (idx & 31) * 4;
        float4 v = ((float4*)h)[idx];
        float* vp = &v.x;
#pragma unroll
        for (int j = 0; j < 4; ++j) {
            float mu = stats[f + j] * invN;
            float var = stats[D + f + j] * invN - mu * mu;
            float sc = gamma[f + j] * rsqrtf(var + BN_EPS);
            float val = (vp[j] - mu) * sc + beta[f + j];
            vp[j] = fmaxf(val, 0.f);
        }
        ((float4*)h)[idx] = v;
    }
}

// ---------------- global_add_pool (batch is sorted) ----------------
__global__ void pool_kernel(const float* __restrict__ h, const int* __restrict__ batch,
                            float* __restrict__ g) {
    int f = threadIdx.x;  // 128 threads
    int r0 = blockIdx.x * POOL_ROWS;
    if (r0 >= N_NODES) return;
    int rend = r0 + POOL_ROWS;
    if (rend > N_NODES) rend = N_NODES;
    int cur = batch[r0];
    float acc = 0.f;
    for (int r = r0; r < rend; ++r) {
        int b = batch[r];
        if (b != cur) {
            atomicAdd(&g[cur * D + f], acc);
            acc = 0.f;
            cur = b;
        }
        acc += h[(size_t)r * D + f];
    }
    atomicAdd(&g[cur * D + f], acc);
}

// ---------------- MLP head: 64x128 -> 128 -> 64 -> 10 ----------------
__launch_bounds__(512)
__global__ void head_kernel(const float* __restrict__ g,
                            const float* __restrict__ fcw1, const float* __restrict__ fcb1,
                            const float* __restrict__ fcw2, const float* __restrict__ fcb2,
                            const float* __restrict__ fcw3, const float* __restrict__ fcb3,
                            float* __restrict__ out) {
    __shared__ float G[64][128];
    __shared__ float T1[64][128];
    __shared__ float T2[64][64];
    int tid = threadIdx.x;
#pragma unroll
    for (int i = 0; i < 4; ++i) {
        int slot = tid + i * 512;  // 2048 float4 slots
        ((float4*)G)[slot] = ((const float4*)g)[slot];
    }
    __syncthreads();
#pragma unroll 1
    for (int rep = 0; rep < 16; ++rep) {
        int o = tid + rep * 512;
        int r = o >> 7, c = o & 127;
        float acc = fcb1[c];
        for (int k = 0; k < 128; ++k) acc = fmaf(G[r][k], fcw1[k * 128 + c], acc);
        T1[r][c] = fmaxf(acc, 0.f);
    }
    __syncthreads();
#pragma unroll 1
    for (int rep = 0; rep < 8; ++rep) {
        int o = tid + rep * 512;
        int r = o >> 6, c = o & 63;
        float acc = fcb2[c];
        for (int k = 0; k < 128; ++k) acc = fmaf(T1[r][k], fcw2[k * 64 + c], acc);
        T2[r][c] = fmaxf(acc, 0.f);
    }
    __syncthreads();
    // 640 outputs with 512 threads: strided loop (R0 bug: `if (tid<640)` left
    // outputs 512..639 unwritten)
    for (int o = tid; o < N_GRAPHS * N_CLASS; o += 512) {
        int r = o / 10, c = o % 10;
        float acc = fcb3[c];
        for (int k = 0; k < 64; ++k) acc = fmaf(T2[r][k], fcw3[k * 10 + c], acc);
        out[o] = acc;
    }
}

extern "C" void kernel_launch(void* const* d_in, const int* in_sizes, int n_in,
                              void* d_out, int out_size, void* d_ws, size_t ws_size,
                              hipStream_t stream) {
    const float* x       = (const float*)d_in[0];
    const int* edge_index= (const int*)d_in[1];
    const int* batch     = (const int*)d_in[2];
    const float* W1      = (const float*)d_in[3];
    const float* b1      = (const float*)d_in[4];
    const float* W2      = (const float*)d_in[5];
    const float* b2      = (const float*)d_in[6];
    const float* gamma   = (const float*)d_in[7];
    const float* beta    = (const float*)d_in[8];
    const float* eps     = (const float*)d_in[9];
    const float* fcw1    = (const float*)d_in[10];
    const float* fcb1    = (const float*)d_in[11];
    const float* fcw2    = (const float*)d_in[12];
    const float* fcb2    = (const float*)d_in[13];
    const float* fcw3    = (const float*)d_in[14];
    const float* fcb3    = (const float*)d_in[15];
    float* out = (float*)d_out;

    char* ws = (char*)d_ws;
    size_t off = 0;
    auto alloc = [&](size_t bytes) -> void* {
        void* p = ws + off;
        off = (off + bytes + 255) & ~(size_t)255;
        return p;
    };
    float* hbuf    = (float*)alloc((size_t)N_NODES * D * 4);   // 51.2 MB
    float* z0buf   = (float*)alloc((size_t)N_NODES * D * 4);   // 51.2 MB
    int* colidx    = (int*)alloc((size_t)N_EDGES * 4);         // 6.4 MB
    int* rowptr    = (int*)alloc((size_t)(N_NODES + 1) * 4);
    int* cursor    = (int*)alloc((size_t)N_NODES * 4);
    int* counts    = (int*)alloc((size_t)N_NODES * 4);
    int* chunkSum  = (int*)alloc(NCHUNKS * 4);
    int* chunkOff  = (int*)alloc(NCHUNKS * 4);
    float* stats   = (float*)alloc(2 * D * 4);
    float* gpool   = (float*)alloc((size_t)N_GRAPHS * D * 4);

    const int* srcArr = edge_index;
    const int* dstArr = edge_index + N_EDGES;

    // ---- CSR build (repeated every call; deterministic) ----
    zero_u32_kernel<<<(N_NODES + 255) / 256, 256, 0, stream>>>((unsigned int*)counts, N_NODES);
    hist_kernel<<<2048, 256, 0, stream>>>(dstArr, counts);
    scan1_kernel<<<NCHUNKS, 256, 0, stream>>>(counts, chunkSum);
    scan2_kernel<<<1, 64, 0, stream>>>(chunkSum, chunkOff, rowptr);
    scan3_kernel<<<NCHUNKS, 256, 0, stream>>>(counts, chunkOff, rowptr, cursor);
    fill_kernel<<<2048, 256, 0, stream>>>(srcArr, dstArr, cursor, colidx);

    // ---- StandardScaler ----
    zero_u32_kernel<<<1, 256, 0, stream>>>((unsigned int*)stats, 2 * D);
    colstats_kernel<<<(N_NODES + 255) / 256, 128, 0, stream>>>(x, stats);
    standardize_kernel<<<2048, 256, 0, stream>>>(x, stats, hbuf);

    // ---- GIN layers ----
    for (int l = 0; l < N_LAYERS; ++l) {
        agg_kernel<<<N_NODES / 2, 256, 0, stream>>>(hbuf, rowptr, colidx, eps, l, z0buf);
        zero_u32_kernel<<<1, 256, 0, stream>>>((unsigned int*)stats, 2 * D);
        mlp_kernel<<<(N_NODES + 63) / 64, 256, 0, stream>>>(
            z0buf, W1 + (size_t)l * D * D, b1 + (size_t)l * D,
            W2 + (size_t)l * D * D, b2 + (size_t)l * D, hbuf, stats);
        bn_relu_kernel<<<2048, 256, 0, stream>>>(hbuf, stats, gamma + (size_t)l * D,
                                                 beta + (size_t)l * D);
    }

    // ---- pool + head ----
    zero_u32_kernel<<<(N_GRAPHS * D + 255) / 256, 256, 0, stream>>>((unsigned int*)gpool, N_GRAPHS * D);
    pool_kernel<<<(N_NODES + POOL_ROWS - 1) / POOL_ROWS, 128, 0, stream>>>(hbuf, batch, gpool);
    head_kernel<<<1, 512, 0, stream>>>(gpool, fcw1, fcb1, fcw2, fcb2, fcw3, fcb3, out);
}

// Round 6
// 1020.393 us; speedup vs baseline: 2.4872x; 2.4872x over previous
//
#include <hip/hip_runtime.h>
#include <hip/hip_bf16.h>

#define N_NODES 100000
#define N_EDGES 1600000
#define D 128
#define N_LAYERS 4
#define N_GRAPHS 64
#define N_CLASS 10
#define BN_EPS 1e-5f

#define CHUNK 2048
#define NCHUNKS 49  // ceil(100000/2048)
#define POOL_ROWS 128
#define LDK 136     // padded LDS row length in bf16 elems (272B = 68 dw = 4 mod 32 banks)

typedef __attribute__((ext_vector_type(8))) short bf16x8;   // 8 bf16 = 4 VGPRs
typedef __attribute__((ext_vector_type(4))) float f32x4;    // MFMA acc

__device__ inline float b2f(ushort u) {
    return __builtin_bit_cast(float, (unsigned)u << 16);
}
__device__ inline ushort f2b(float f) {  // RNE bf16
    unsigned u = __builtin_bit_cast(unsigned, f);
    return (ushort)((u + 0x7fffu + ((u >> 16) & 1u)) >> 16);
}

// ---------------- utility: zero a u32 buffer ----------------
__global__ void zero_u32_kernel(unsigned int* __restrict__ p, int n) {
    int i = blockIdx.x * blockDim.x + threadIdx.x;
    if (i < n) p[i] = 0u;
}

// ---------------- CSR build ----------------
__global__ void hist_kernel(const int* __restrict__ dst, int* __restrict__ counts) {
    int stride = gridDim.x * blockDim.x;
    for (int e = blockIdx.x * blockDim.x + threadIdx.x; e < N_EDGES; e += stride)
        atomicAdd(&counts[dst[e]], 1);
}

__global__ void scan1_kernel(const int* __restrict__ counts, int* __restrict__ chunkSum) {
    __shared__ int red[4];
    int b = blockIdx.x, t = threadIdx.x;
    int base = b * CHUNK;
    int s = 0;
    for (int i = t; i < CHUNK; i += 256) {
        int g = base + i;
        s += (g < N_NODES) ? counts[g] : 0;
    }
    for (int off = 32; off > 0; off >>= 1) s += __shfl_down(s, off, 64);
    if ((t & 63) == 0) red[t >> 6] = s;
    __syncthreads();
    if (t == 0) chunkSum[b] = red[0] + red[1] + red[2] + red[3];
}

__global__ void scan2_kernel(const int* __restrict__ chunkSum, int* __restrict__ chunkOff,
                             int* __restrict__ rowptr) {
    if (threadIdx.x == 0) {
        int run = 0;
        for (int i = 0; i < NCHUNKS; ++i) { chunkOff[i] = run; run += chunkSum[i]; }
        rowptr[N_NODES] = run;
    }
}

__global__ void scan3_kernel(const int* __restrict__ counts, const int* __restrict__ chunkOff,
                             int* __restrict__ rowptr, int* __restrict__ cursor) {
    __shared__ int lds[256];
    int b = blockIdx.x, t = threadIdx.x;
    int base = b * CHUNK + t * 8;
    int v[8];
    int run = 0;
#pragma unroll
    for (int i = 0; i < 8; ++i) {
        int g = base + i;
        int c = (g < N_NODES) ? counts[g] : 0;
        v[i] = run; run += c;
    }
    lds[t] = run;
    __syncthreads();
    for (int off = 1; off < 256; off <<= 1) {
        int xv = (t >= off) ? lds[t - off] : 0;
        __syncthreads();
        lds[t] += xv;
        __syncthreads();
    }
    int tpre = lds[t] - run;
    int o0 = chunkOff[b];
#pragma unroll
    for (int i = 0; i < 8; ++i) {
        int g = base + i;
        if (g < N_NODES) { int val = o0 + tpre + v[i]; rowptr[g] = val; cursor[g] = val; }
    }
}

__global__ void fill_kernel(const int* __restrict__ src, const int* __restrict__ dst,
                            int* __restrict__ cursor, int* __restrict__ colidx) {
    int stride = gridDim.x * blockDim.x;
    for (int e = blockIdx.x * blockDim.x + threadIdx.x; e < N_EDGES; e += stride) {
        int d = dst[e];
        int p = atomicAdd(&cursor[d], 1);
        colidx[p] = src[e];
    }
}

// ---------------- standardization ----------------
__global__ void colstats_kernel(const float* __restrict__ x, float* __restrict__ stats) {
    __shared__ float ssum[D];
    __shared__ float ssq[D];
    int tid = threadIdx.x;
    if (tid < D) { ssum[tid] = 0.f; ssq[tid] = 0.f; }
    __syncthreads();
    int f4 = (tid & 31) * 4;
    int rsub = tid >> 5;
    int r0 = blockIdx.x * 128;
    int rend = r0 + 128;
    if (rend > N_NODES) rend = N_NODES;
    float4 ps = make_float4(0.f, 0.f, 0.f, 0.f);
    float4 pq = make_float4(0.f, 0.f, 0.f, 0.f);
    for (int r = r0 + rsub; r < rend; r += 8) {
        float4 v = *(const float4*)&x[(size_t)r * D + f4];
        ps.x += v.x; ps.y += v.y; ps.z += v.z; ps.w += v.w;
        pq.x += v.x * v.x; pq.y += v.y * v.y; pq.z += v.z * v.z; pq.w += v.w * v.w;
    }
    atomicAdd(&ssum[f4 + 0], ps.x); atomicAdd(&ssum[f4 + 1], ps.y);
    atomicAdd(&ssum[f4 + 2], ps.z); atomicAdd(&ssum[f4 + 3], ps.w);
    atomicAdd(&ssq[f4 + 0], pq.x);  atomicAdd(&ssq[f4 + 1], pq.y);
    atomicAdd(&ssq[f4 + 2], pq.z);  atomicAdd(&ssq[f4 + 3], pq.w);
    __syncthreads();
    if (tid < D) {
        atomicAdd(&stats[tid], ssum[tid]);
        atomicAdd(&stats[D + tid], ssq[tid]);
    }
}

// writes bf16 h
__global__ void standardize_kernel(const float* __restrict__ x, const float* __restrict__ stats,
                                   ushort* __restrict__ h) {
    const float invN = 1.f / (float)N_NODES;
    int stride = gridDim.x * blockDim.x;
    const int total = N_NODES * (D / 4);
    for (int idx = blockIdx.x * blockDim.x + threadIdx.x; idx < total; idx += stride) {
        int f = (idx & 31) * 4;
        float4 v = ((const float4*)x)[idx];
        float o[4];
        float vv[4] = {v.x, v.y, v.z, v.w};
#pragma unroll
        for (int j = 0; j < 4; ++j) {
            float mu = stats[f + j] * invN;
            float sd = sqrtf(stats[D + f + j] * invN - mu * mu);
            o[j] = (vv[j] - mu) / sd;
        }
        ((ushort4*)h)[idx] = make_ushort4(f2b(o[0]), f2b(o[1]), f2b(o[2]), f2b(o[3]));
    }
}

// ---------------- GIN aggregation (bf16 in/out, fp32 accumulate) ----------------
__global__ void agg_kernel(const ushort* __restrict__ h, const int* __restrict__ rowptr,
                           const int* __restrict__ colidx, const float* __restrict__ eps, int l,
                           ushort* __restrict__ z0) {
    int node = blockIdx.x * 8 + (threadIdx.x >> 5);
    int f4 = (threadIdx.x & 31) * 4;
    const ushort* hp = h + f4;
    ushort4 c = *(const ushort4*)&hp[(size_t)node * D];
    float se = 1.f + eps[l];
    float ax = se * b2f(c.x), ay = se * b2f(c.y), az = se * b2f(c.z), aw = se * b2f(c.w);
    int e = rowptr[node], e1 = rowptr[node + 1];
    for (; e + 2 <= e1; e += 2) {
        int s0 = colidx[e];
        int s1 = colidx[e + 1];
        ushort4 v0 = *(const ushort4*)&hp[(size_t)s0 * D];
        ushort4 v1 = *(const ushort4*)&hp[(size_t)s1 * D];
        ax += b2f(v0.x) + b2f(v1.x); ay += b2f(v0.y) + b2f(v1.y);
        az += b2f(v0.z) + b2f(v1.z); aw += b2f(v0.w) + b2f(v1.w);
    }
    if (e < e1) {
        int s0 = colidx[e];
        ushort4 v0 = *(const ushort4*)&hp[(size_t)s0 * D];
        ax += b2f(v0.x); ay += b2f(v0.y); az += b2f(v0.z); aw += b2f(v0.w);
    }
    *(ushort4*)&z0[(size_t)node * D + f4] = make_ushort4(f2b(ax), f2b(ay), f2b(az), f2b(aw));
}

// ---------------- weight prep: Wt[n][k] bf16 for both MLP weights, all layers ------------
// wt layout: [w(0=W1,1=W2)][layer][n][k]; coalesced 2B writes, scattered cached reads
__global__ void prep_wt_kernel(const float* __restrict__ W1, const float* __restrict__ W2,
                               ushort* __restrict__ wt) {
    int idx = blockIdx.x * blockDim.x + threadIdx.x;  // 131072 total
    int w = idx >> 16;
    int rem = idx & 65535;
    int l = rem >> 14;
    int nk = rem & 16383;
    int n = nk >> 7;
    int k = nk & 127;
    const float* W = w ? W2 : W1;
    wt[idx] = f2b(W[((size_t)(l * D + k)) * D + n]);
}

// ---------------- fused MFMA MLP: z2 = relu(relu(z0@W1+b1)@W2+b2), + BN stats ------------
// 128x128 block tile, 4 waves x (32 rows x 128 cols), mfma_f32_16x16x32_bf16.
// A: row=lane&15, k=(lane>>4)*8+e ; B(Wt[n][k]): col=lane&15, same k ; D: col=lane&15,
// row=(lane>>4)*4+r (m89-verified). LDS rows padded to 136 (<=2-way bank conflicts).
__launch_bounds__(256, 2)
__global__ void mlp_mfma_kernel(const ushort* __restrict__ z0,
                                const ushort* __restrict__ wt1, const float* __restrict__ b1,
                                const ushort* __restrict__ wt2, const float* __restrict__ b2,
                                ushort* __restrict__ out, float* __restrict__ stats) {
    __shared__ ushort As[128 * LDK];
    __shared__ ushort Bs[128 * LDK];
    __shared__ float Ssum[D];
    __shared__ float Ssq[D];

    int tid = threadIdx.x;
    int lane = tid & 63;
    int wave = tid >> 6;           // 0..3
    int rb = blockIdx.x * 128;
    int lrow = lane & 15;
    int lk = lane >> 4;            // 0..3
    int klane = lk * 8;
    int wr0 = wave * 32;

    if (tid < D) { Ssum[tid] = 0.f; Ssq[tid] = 0.f; }

    // ---- stage A (z0 tile, row-guarded) and B (wt1) ----
#pragma unroll
    for (int i = 0; i < 8; ++i) {
        int c2 = tid + i * 256;        // 0..2047 16B-chunks
        int row = c2 >> 4;
        int cc = (c2 & 15) * 8;
        int gr = rb + row;
        bf16x8 v;
#pragma unroll
        for (int e = 0; e < 8; ++e) v[e] = 0;
        if (gr < N_NODES) v = *(const bf16x8*)&z0[(size_t)gr * D + cc];
        *(bf16x8*)&As[row * LDK + cc] = v;
        *(bf16x8*)&Bs[row * LDK + cc] = *(const bf16x8*)&wt1[c2 * 8];
    }
    __syncthreads();

    f32x4 acc[2][8];
#pragma unroll
    for (int a = 0; a < 2; ++a)
#pragma unroll
        for (int b = 0; b < 8; ++b)
#pragma unroll
            for (int r = 0; r < 4; ++r) acc[a][b][r] = 0.f;

    // ---- GEMM1 ----
#pragma unroll
    for (int ks = 0; ks < 4; ++ks) {
        int k0 = ks * 32 + klane;
        bf16x8 a0 = *(const bf16x8*)&As[(wr0 + lrow) * LDK + k0];
        bf16x8 a1 = *(const bf16x8*)&As[(wr0 + 16 + lrow) * LDK + k0];
#pragma unroll
        for (int ct = 0; ct < 8; ++ct) {
            bf16x8 bb = *(const bf16x8*)&Bs[(ct * 16 + lrow) * LDK + k0];
            acc[0][ct] = __builtin_amdgcn_mfma_f32_16x16x32_bf16(a0, bb, acc[0][ct], 0, 0, 0);
            acc[1][ct] = __builtin_amdgcn_mfma_f32_16x16x32_bf16(a1, bb, acc[1][ct], 0, 0, 0);
        }
    }
    __syncthreads();   // all GEMM1 LDS reads complete before overwrite

    // ---- z1 = relu(acc + b1) -> As (bf16); restage Bs with wt2 ----
#pragma unroll
    for (int rt = 0; rt < 2; ++rt)
#pragma unroll
        for (int ct = 0; ct < 8; ++ct) {
            int col = ct * 16 + lrow;
            float bias = b1[col];
#pragma unroll
            for (int r = 0; r < 4; ++r) {
                int row = wr0 + rt * 16 + lk * 4 + r;
                As[row * LDK + col] = f2b(fmaxf(acc[rt][ct][r] + bias, 0.f));
            }
        }
#pragma unroll
    for (int i = 0; i < 8; ++i) {
        int c2 = tid + i * 256;
        int row = c2 >> 4;
        int cc = (c2 & 15) * 8;
        *(bf16x8*)&Bs[row * LDK + cc] = *(const bf16x8*)&wt2[c2 * 8];
    }
#pragma unroll
    for (int a = 0; a < 2; ++a)
#pragma unroll
        for (int b = 0; b < 8; ++b)
#pragma unroll
            for (int r = 0; r < 4; ++r) acc[a][b][r] = 0.f;
    __syncthreads();

    // ---- GEMM2 ----
#pragma unroll
    for (int ks = 0; ks < 4; ++ks) {
        int k0 = ks * 32 + klane;
        bf16x8 a0 = *(const bf16x8*)&As[(wr0 + lrow) * LDK + k0];
        bf16x8 a1 = *(const bf16x8*)&As[(wr0 + 16 + lrow) * LDK + k0];
#pragma unroll
        for (int ct = 0; ct < 8; ++ct) {
            bf16x8 bb = *(const bf16x8*)&Bs[(ct * 16 + lrow) * LDK + k0];
            acc[0][ct] = __builtin_amdgcn_mfma_f32_16x16x32_bf16(a0, bb, acc[0][ct], 0, 0, 0);
            acc[1][ct] = __builtin_amdgcn_mfma_f32_16x16x32_bf16(a1, bb, acc[1][ct], 0, 0, 0);
        }
    }
    __syncthreads();   // all GEMM2 LDS reads complete

    // ---- z2 epilogue: BN stats (fp32, row-guarded) + stage bf16 into Bs ----
#pragma unroll
    for (int rt = 0; rt < 2; ++rt)
#pragma unroll
        for (int ct = 0; ct < 8; ++ct) {
            int col = ct * 16 + lrow;
            float bias = b2[col];
            float s = 0.f, sq = 0.f;
#pragma unroll
            for (int r = 0; r < 4; ++r) {
                int row = wr0 + rt * 16 + lk * 4 + r;
                float v = fmaxf(acc[rt][ct][r] + bias, 0.f);
                Bs[row * LDK + col] = f2b(v);
                if (rb + row < N_NODES) { s += v; sq += v * v; }
            }
            atomicAdd(&Ssum[col], s);
            atomicAdd(&Ssq[col], sq);
        }
    __syncthreads();

    // ---- coalesced bf16 store + global stats ----
#pragma unroll
    for (int i = 0; i < 8; ++i) {
        int c2 = tid + i * 256;
        int row = c2 >> 4;
        int cc = (c2 & 15) * 8;
        int gr = rb + row;
        if (gr < N_NODES)
            *(bf16x8*)&out[(size_t)gr * D + cc] = *(const bf16x8*)&Bs[row * LDK + cc];
    }
    if (tid < D) {
        atomicAdd(&stats[tid], Ssum[tid]);
        atomicAdd(&stats[D + tid], Ssq[tid]);
    }
}

// ---------------- BN prep: fold stats into per-feature affine A,B ----------------
__global__ void bnprep_kernel(const float* __restrict__ stats, const float* __restrict__ gamma,
                              const float* __restrict__ beta, float* __restrict__ ab) {
    int f = threadIdx.x;
    if (f < D) {
        const float invN = 1.f / (float)N_NODES;
        float mu = stats[f] * invN;
        float var = stats[D + f] * invN - mu * mu;
        float A = gamma[f] * rsqrtf(var + BN_EPS);
        ab[f] = A;
        ab[D + f] = beta[f] - mu * A;
    }
}

// ---------------- BN apply + relu, in place on bf16 h ----------------
__global__ void bn_relu_kernel(ushort* __restrict__ h, const float* __restrict__ ab) {
    int stride = gridDim.x * blockDim.x;
    const int total = N_NODES * (D / 8);
    for (int idx = blockIdx.x * blockDim.x + threadIdx.x; idx < total; idx += stride) {
        int f8 = (idx & 15) * 8;
        uint4 v = ((const uint4*)h)[idx];
        unsigned vv[4] = {v.x, v.y, v.z, v.w};
        unsigned rr[4];
#pragma unroll
        for (int q = 0; q < 4; ++q) {
            int f = f8 + q * 2;
            float xlo = __builtin_bit_cast(float, vv[q] << 16);
            float xhi = __builtin_bit_cast(float, vv[q] & 0xffff0000u);
            float ylo = fmaxf(xlo * ab[f] + ab[D + f], 0.f);
            float yhi = fmaxf(xhi * ab[f + 1] + ab[D + f + 1], 0.f);
            rr[q] = (unsigned)f2b(ylo) | ((unsigned)f2b(yhi) << 16);
        }
        uint4 o;
        o.x = rr[0]; o.y = rr[1]; o.z = rr[2]; o.w = rr[3];
        ((uint4*)h)[idx] = o;
    }
}

// ---------------- global_add_pool (batch sorted, bf16 h) ----------------
__global__ void pool_kernel(const ushort* __restrict__ h, const int* __restrict__ batch,
                            float* __restrict__ g) {
    int tid = threadIdx.x;
    int f4 = (tid & 31) * 4;
    int rsub = tid >> 5;
    int r0 = blockIdx.x * POOL_ROWS;
    int rend = r0 + POOL_ROWS;
    if (rend > N_NODES) rend = N_NODES;
    float4 acc = make_float4(0.f, 0.f, 0.f, 0.f);
    int cur = -1;
    for (int r = r0 + rsub; r < rend; r += 8) {
        int b = batch[r];
        if (b != cur) {
            if (cur >= 0) {
                atomicAdd(&g[cur * D + f4 + 0], acc.x);
                atomicAdd(&g[cur * D + f4 + 1], acc.y);
                atomicAdd(&g[cur * D + f4 + 2], acc.z);
                atomicAdd(&g[cur * D + f4 + 3], acc.w);
            }
            acc = make_float4(0.f, 0.f, 0.f, 0.f);
            cur = b;
        }
        ushort4 v = *(const ushort4*)&h[(size_t)r * D + f4];
        acc.x += b2f(v.x); acc.y += b2f(v.y); acc.z += b2f(v.z); acc.w += b2f(v.w);
    }
    if (cur >= 0) {
        atomicAdd(&g[cur * D + f4 + 0], acc.x);
        atomicAdd(&g[cur * D + f4 + 1], acc.y);
        atomicAdd(&g[cur * D + f4 + 2], acc.z);
        atomicAdd(&g[cur * D + f4 + 3], acc.w);
    }
}

// ---------------- MLP head: 64x128 -> 128 -> 64 -> 10 (fp32) ----------------
__launch_bounds__(512)
__global__ void head_kernel(const float* __restrict__ g,
                            const float* __restrict__ fcw1, const float* __restrict__ fcb1,
                            const float* __restrict__ fcw2, const float* __restrict__ fcb2,
                            const float* __restrict__ fcw3, const float* __restrict__ fcb3,
                            float* __restrict__ out) {
    __shared__ float G[64][128];
    __shared__ float T1[64][128];
    __shared__ float T2[64][64];
    int tid = threadIdx.x;
#pragma unroll
    for (int i = 0; i < 4; ++i) {
        int slot = tid + i * 512;
        ((float4*)G)[slot] = ((const float4*)g)[slot];
    }
    __syncthreads();
#pragma unroll 1
    for (int rep = 0; rep < 16; ++rep) {
        int o = tid + rep * 512;
        int r = o >> 7, c = o & 127;
        float acc = fcb1[c];
        for (int k = 0; k < 128; ++k) acc = fmaf(G[r][k], fcw1[k * 128 + c], acc);
        T1[r][c] = fmaxf(acc, 0.f);
    }
    __syncthreads();
#pragma unroll 1
    for (int rep = 0; rep < 8; ++rep) {
        int o = tid + rep * 512;
        int r = o >> 6, c = o & 63;
        float acc = fcb2[c];
        for (int k = 0; k < 128; ++k) acc = fmaf(T1[r][k], fcw2[k * 64 + c], acc);
        T2[r][c] = fmaxf(acc, 0.f);
    }
    __syncthreads();
    for (int o = tid; o < N_GRAPHS * N_CLASS; o += 512) {
        int r = o / 10, c = o % 10;
        float acc = fcb3[c];
        for (int k = 0; k < 64; ++k) acc = fmaf(T2[r][k], fcw3[k * 10 + c], acc);
        out[o] = acc;
    }
}

extern "C" void kernel_launch(void* const* d_in, const int* in_sizes, int n_in,
                              void* d_out, int out_size, void* d_ws, size_t ws_size,
                              hipStream_t stream) {
    const float* x        = (const float*)d_in[0];
    const int* edge_index = (const int*)d_in[1];
    const int* batch      = (const int*)d_in[2];
    const float* W1       = (const float*)d_in[3];
    const float* b1       = (const float*)d_in[4];
    const float* W2       = (const float*)d_in[5];
    const float* b2       = (const float*)d_in[6];
    const float* gamma    = (const float*)d_in[7];
    const float* beta     = (const float*)d_in[8];
    const float* eps      = (const float*)d_in[9];
    const float* fcw1     = (const float*)d_in[10];
    const float* fcb1     = (const float*)d_in[11];
    const float* fcw2     = (const float*)d_in[12];
    const float* fcb2     = (const float*)d_in[13];
    const float* fcw3     = (const float*)d_in[14];
    const float* fcb3     = (const float*)d_in[15];
    float* out = (float*)d_out;

    char* ws = (char*)d_ws;
    size_t off = 0;
    auto alloc = [&](size_t bytes) -> void* {
        void* p = ws + off;
        off = (off + bytes + 255) & ~(size_t)255;
        return p;
    };
    ushort* hbuf   = (ushort*)alloc((size_t)N_NODES * D * 2);     // 25.6 MB bf16
    ushort* z0buf  = (ushort*)alloc((size_t)N_NODES * D * 2);     // 25.6 MB bf16
    ushort* wtbuf  = (ushort*)alloc((size_t)2 * N_LAYERS * D * D * 2);  // 256 KB
    int* colidx    = (int*)alloc((size_t)N_EDGES * 4);
    int* rowptr    = (int*)alloc((size_t)(N_NODES + 1) * 4);
    int* cursor    = (int*)alloc((size_t)N_NODES * 4);
    int* counts    = (int*)alloc((size_t)N_NODES * 4);
    int* chunkSum  = (int*)alloc(NCHUNKS * 4);
    int* chunkOff  = (int*)alloc(NCHUNKS * 4);
    float* stats   = (float*)alloc(4 * D * 4);   // [sum | sumsq | bnA | bnB]
    float* gpool   = (float*)alloc((size_t)N_GRAPHS * D * 4);

    const int* srcArr = edge_index;
    const int* dstArr = edge_index + N_EDGES;

    // ---- CSR build ----
    zero_u32_kernel<<<(N_NODES + 255) / 256, 256, 0, stream>>>((unsigned int*)counts, N_NODES);
    hist_kernel<<<2048, 256, 0, stream>>>(dstArr, counts);
    scan1_kernel<<<NCHUNKS, 256, 0, stream>>>(counts, chunkSum);
    scan2_kernel<<<1, 64, 0, stream>>>(chunkSum, chunkOff, rowptr);
    scan3_kernel<<<NCHUNKS, 256, 0, stream>>>(counts, chunkOff, rowptr, cursor);
    fill_kernel<<<2048, 256, 0, stream>>>(srcArr, dstArr, cursor, colidx);

    // ---- StandardScaler (h -> bf16) ----
    zero_u32_kernel<<<1, 256, 0, stream>>>((unsigned int*)stats, 2 * D);
    colstats_kernel<<<(N_NODES + 127) / 128, 256, 0, stream>>>(x, stats);
    standardize_kernel<<<2048, 256, 0, stream>>>(x, stats, hbuf);

    // ---- weight prep (transposed bf16, all layers) ----
    prep_wt_kernel<<<512, 256, 0, stream>>>(W1, W2, wtbuf);

    // ---- GIN layers ----
    for (int l = 0; l < N_LAYERS; ++l) {
        agg_kernel<<<N_NODES / 8, 256, 0, stream>>>(hbuf, rowptr, colidx, eps, l, z0buf);
        zero_u32_kernel<<<1, 256, 0, stream>>>((unsigned int*)stats, 2 * D);
        mlp_mfma_kernel<<<(N_NODES + 127) / 128, 256, 0, stream>>>(
            z0buf, wtbuf + (size_t)l * D * D, b1 + (size_t)l * D,
            wtbuf + (size_t)(N_LAYERS + l) * D * D, b2 + (size_t)l * D, hbuf, stats);
        bnprep_kernel<<<1, 128, 0, stream>>>(stats, gamma + (size_t)l * D,
                                             beta + (size_t)l * D, stats + 2 * D);
        bn_relu_kernel<<<2048, 256, 0, stream>>>(hbuf, stats + 2 * D);
    }

    // ---- pool + head ----
    zero_u32_kernel<<<(N_GRAPHS * D + 255) / 256, 256, 0, stream>>>((unsigned int*)gpool, N_GRAPHS * D);
    pool_kernel<<<(N_NODES + POOL_ROWS - 1) / POOL_ROWS, 256, 0, stream>>>(hbuf, batch, gpool);
    head_kernel<<<1, 512, 0, stream>>>(gpool, fcw1, fcb1, fcw2, fcb2, fcw3, fcb3, out);
}

// Round 7
// 851.354 us; speedup vs baseline: 2.9811x; 1.1986x over previous
//
#include <hip/hip_runtime.h>
#include <hip/hip_bf16.h>
#include <math.h>

#define N_NODES 100000
#define N_EDGES 1600000
#define D 128
#define N_LAYERS 4
#define N_GRAPHS 64
#define N_CLASS 10
#define BN_EPS 1e-5f

#define POOL_ROWS 128
#define LDK 136     // padded LDS row length in bf16 elems (272B = 68 dw = 4 mod 32 banks)

// bucket CSR build params
#define EB_CHUNK 4096
#define EDGE_BLOCKS ((N_EDGES + EB_CHUNK - 1) / EB_CHUNK)   // 391
#define NPB 512                                             // nodes per bucket (dst >> 9)
#define NB ((N_NODES + NPB - 1) / NPB)                      // 196

typedef __attribute__((ext_vector_type(8))) short bf16x8;   // 8 bf16 = 4 VGPRs
typedef __attribute__((ext_vector_type(4))) float f32x4;    // MFMA acc

__device__ inline float b2f(ushort u) {
    return __builtin_bit_cast(float, (unsigned)u << 16);
}
__device__ inline ushort f2b(float f) {  // RNE bf16
    unsigned u = __builtin_bit_cast(unsigned, f);
    return (ushort)((u + 0x7fffu + ((u >> 16) & 1u)) >> 16);
}

// ---------------- utility: zero a u32 buffer ----------------
__global__ void zero_u32_kernel(unsigned int* __restrict__ p, int n) {
    int i = blockIdx.x * blockDim.x + threadIdx.x;
    if (i < n) p[i] = 0u;
}

// ================= bucketed CSR build =================
// R6: replaces hist/scan/fill. fill had 107MB WRITE_SIZE for a 6.4MB colidx
// (16x line amplification from cross-XCD scattered 4B stores). Here every
// global write region is block-contiguous, so lines stay in one L2.

// Phase 1a: per-bucket edge counts (LDS hist -> 1 atomic per bucket per block)
__global__ void bucket_count_kernel(const int* __restrict__ dst, int* __restrict__ bucketCount) {
    __shared__ int bc[NB];
    int tid = threadIdx.x;
    if (tid < NB) bc[tid] = 0;
    __syncthreads();
    int base = blockIdx.x * EB_CHUNK;
#pragma unroll
    for (int i = 0; i < 16; ++i) {
        int e = base + i * 256 + tid;
        if (e < N_EDGES) atomicAdd(&bc[dst[e] >> 9], 1);
    }
    __syncthreads();
    if (tid < NB && bc[tid]) atomicAdd(&bucketCount[tid], bc[tid]);
}

// Phase 1b: exclusive scan of the 196 bucket counts (single block)
__global__ void bucket_scan_kernel(const int* __restrict__ bucketCount,
                                   int* __restrict__ bucketBase, int* __restrict__ bucketCursor) {
    __shared__ int lds[256];
    int tid = threadIdx.x;
    int v = (tid < NB) ? bucketCount[tid] : 0;
    lds[tid] = v;
    __syncthreads();
    for (int off = 1; off < 256; off <<= 1) {
        int x = (tid >= off) ? lds[tid - off] : 0;
        __syncthreads();
        lds[tid] += x;
        __syncthreads();
    }
    int excl = lds[tid] - v;
    if (tid < NB) { bucketBase[tid] = excl; bucketCursor[tid] = excl; }
    if (tid == NB - 1) bucketBase[NB] = excl + v;
}

// Phase 1c: scatter (src,dst) pairs bucket-contiguously. Each block reserves
// a contiguous per-bucket range (ONE atomic per bucket), so its writes are
// ~2.6 contiguous lines per bucket -> ~1.4x amplification instead of 16x.
__global__ void bucket_scatter_kernel(const int* __restrict__ src, const int* __restrict__ dst,
                                      int* __restrict__ bucketCursor, int2* __restrict__ bpairs) {
    __shared__ int lcnt[NB];
    int tid = threadIdx.x;
    if (tid < NB) lcnt[tid] = 0;
    __syncthreads();
    int base = blockIdx.x * EB_CHUNK;
    int s[16], d[16];
#pragma unroll
    for (int i = 0; i < 16; ++i) {
        int e = base + i * 256 + tid;
        if (e < N_EDGES) {
            s[i] = src[e]; d[i] = dst[e];
            atomicAdd(&lcnt[d[i] >> 9], 1);
        } else {
            d[i] = -1;
        }
    }
    __syncthreads();
    if (tid < NB) {
        int c = lcnt[tid];
        lcnt[tid] = c ? atomicAdd(&bucketCursor[tid], c) : 0;
    }
    __syncthreads();
#pragma unroll
    for (int i = 0; i < 16; ++i) {
        if (d[i] >= 0) {
            int p = atomicAdd(&lcnt[d[i] >> 9], 1);
            bpairs[p] = make_int2(s[i], d[i]);
        }
    }
}

// Phase 2: per-bucket CSR finalize. One block per bucket: LDS 512-node hist,
// LDS scan -> rowptr (coalesced), then colidx scatter confined to this
// block's ~33KB window (single-XCD lines, evicted once).
__launch_bounds__(512)
__global__ void csr_build_kernel(const int2* __restrict__ bpairs, const int* __restrict__ bucketBase,
                                 int* __restrict__ rowptr, int* __restrict__ colidx) {
    __shared__ int cnt[NPB];
    __shared__ int cur[NPB];
    int tid = threadIdx.x;
    int b = blockIdx.x;
    int nb0 = b * NPB;
    int ebase = bucketBase[b];
    int eend = bucketBase[b + 1];
    cnt[tid] = 0;
    __syncthreads();
    for (int e = ebase + tid; e < eend; e += 512)
        atomicAdd(&cnt[bpairs[e].y - nb0], 1);
    __syncthreads();
    int v = cnt[tid];
    for (int off = 1; off < 512; off <<= 1) {
        int x = (tid >= off) ? cnt[tid - off] : 0;
        __syncthreads();
        cnt[tid] += x;
        __syncthreads();
    }
    int excl = cnt[tid] - v;
    int node = nb0 + tid;
    if (node < N_NODES) rowptr[node] = ebase + excl;
    cur[tid] = ebase + excl;
    __syncthreads();
    for (int e = ebase + tid; e < eend; e += 512) {
        int2 pr = bpairs[e];
        int p = atomicAdd(&cur[pr.y - nb0], 1);
        colidx[p] = pr.x;
    }
    if (b == 0 && tid == 0) rowptr[N_NODES] = N_EDGES;
}

// ---------------- standardization ----------------
__global__ void colstats_kernel(const float* __restrict__ x, float* __restrict__ stats) {
    __shared__ float ssum[D];
    __shared__ float ssq[D];
    int tid = threadIdx.x;
    if (tid < D) { ssum[tid] = 0.f; ssq[tid] = 0.f; }
    __syncthreads();
    int f4 = (tid & 31) * 4;
    int rsub = tid >> 5;
    int r0 = blockIdx.x * 128;
    int rend = r0 + 128;
    if (rend > N_NODES) rend = N_NODES;
    float4 ps = make_float4(0.f, 0.f, 0.f, 0.f);
    float4 pq = make_float4(0.f, 0.f, 0.f, 0.f);
    for (int r = r0 + rsub; r < rend; r += 8) {
        float4 v = *(const float4*)&x[(size_t)r * D + f4];
        ps.x += v.x; ps.y += v.y; ps.z += v.z; ps.w += v.w;
        pq.x += v.x * v.x; pq.y += v.y * v.y; pq.z += v.z * v.z; pq.w += v.w * v.w;
    }
    atomicAdd(&ssum[f4 + 0], ps.x); atomicAdd(&ssum[f4 + 1], ps.y);
    atomicAdd(&ssum[f4 + 2], ps.z); atomicAdd(&ssum[f4 + 3], ps.w);
    atomicAdd(&ssq[f4 + 0], pq.x);  atomicAdd(&ssq[f4 + 1], pq.y);
    atomicAdd(&ssq[f4 + 2], pq.z);  atomicAdd(&ssq[f4 + 3], pq.w);
    __syncthreads();
    if (tid < D) {
        atomicAdd(&stats[tid], ssum[tid]);
        atomicAdd(&stats[D + tid], ssq[tid]);
    }
}

// writes bf16 h
__global__ void standardize_kernel(const float* __restrict__ x, const float* __restrict__ stats,
                                   ushort* __restrict__ h) {
    const float invN = 1.f / (float)N_NODES;
    int stride = gridDim.x * blockDim.x;
    const int total = N_NODES * (D / 4);
    for (int idx = blockIdx.x * blockDim.x + threadIdx.x; idx < total; idx += stride) {
        int f = (idx & 31) * 4;
        float4 v = ((const float4*)x)[idx];
        float o[4];
        float vv[4] = {v.x, v.y, v.z, v.w};
#pragma unroll
        for (int j = 0; j < 4; ++j) {
            float mu = stats[f + j] * invN;
            float sd = sqrtf(stats[D + f + j] * invN - mu * mu);
            o[j] = (vv[j] - mu) / sd;
        }
        ((ushort4*)h)[idx] = make_ushort4(f2b(o[0]), f2b(o[1]), f2b(o[2]), f2b(o[3]));
    }
}

// ---------------- GIN aggregation with fused BN affine + relu ----------------
// R6: h now stores PRE-BN z2 (bf16); the previous layer's BN (affine ab) and
// outer relu are applied per gathered element here. Layer 0: ab=identity and
// lo=-INF (no relu on standardized x).
__global__ void agg_kernel(const ushort* __restrict__ h, const int* __restrict__ rowptr,
                           const int* __restrict__ colidx, const float* __restrict__ eps, int l,
                           const float* __restrict__ ab, int relu_flag,
                           ushort* __restrict__ z0) {
    int node = blockIdx.x * 8 + (threadIdx.x >> 5);
    int f4 = (threadIdx.x & 31) * 4;
    const ushort* hp = h + f4;
    float A0 = ab[f4 + 0], A1 = ab[f4 + 1], A2 = ab[f4 + 2], A3 = ab[f4 + 3];
    float B0 = ab[D + f4 + 0], B1 = ab[D + f4 + 1], B2 = ab[D + f4 + 2], B3 = ab[D + f4 + 3];
    float lo = relu_flag ? 0.f : -INFINITY;

    ushort4 c = *(const ushort4*)&hp[(size_t)node * D];
    float se = 1.f + eps[l];
    float ax = se * fmaxf(fmaf(b2f(c.x), A0, B0), lo);
    float ay = se * fmaxf(fmaf(b2f(c.y), A1, B1), lo);
    float az = se * fmaxf(fmaf(b2f(c.z), A2, B2), lo);
    float aw = se * fmaxf(fmaf(b2f(c.w), A3, B3), lo);

    int e = rowptr[node], e1 = rowptr[node + 1];
    for (; e + 2 <= e1; e += 2) {
        int s0 = colidx[e];
        int s1 = colidx[e + 1];
        ushort4 v0 = *(const ushort4*)&hp[(size_t)s0 * D];
        ushort4 v1 = *(const ushort4*)&hp[(size_t)s1 * D];
        ax += fmaxf(fmaf(b2f(v0.x), A0, B0), lo) + fmaxf(fmaf(b2f(v1.x), A0, B0), lo);
        ay += fmaxf(fmaf(b2f(v0.y), A1, B1), lo) + fmaxf(fmaf(b2f(v1.y), A1, B1), lo);
        az += fmaxf(fmaf(b2f(v0.z), A2, B2), lo) + fmaxf(fmaf(b2f(v1.z), A2, B2), lo);
        aw += fmaxf(fmaf(b2f(v0.w), A3, B3), lo) + fmaxf(fmaf(b2f(v1.w), A3, B3), lo);
    }
    if (e < e1) {
        int s0 = colidx[e];
        ushort4 v0 = *(const ushort4*)&hp[(size_t)s0 * D];
        ax += fmaxf(fmaf(b2f(v0.x), A0, B0), lo);
        ay += fmaxf(fmaf(b2f(v0.y), A1, B1), lo);
        az += fmaxf(fmaf(b2f(v0.z), A2, B2), lo);
        aw += fmaxf(fmaf(b2f(v0.w), A3, B3), lo);
    }
    *(ushort4*)&z0[(size_t)node * D + f4] = make_ushort4(f2b(ax), f2b(ay), f2b(az), f2b(aw));
}

// ---------------- weight prep: Wt[n][k] bf16 for both MLP weights, all layers ------------
__global__ void prep_wt_kernel(const float* __restrict__ W1, const float* __restrict__ W2,
                               ushort* __restrict__ wt) {
    int idx = blockIdx.x * blockDim.x + threadIdx.x;  // 131072 total
    int w = idx >> 16;
    int rem = idx & 65535;
    int l = rem >> 14;
    int nk = rem & 16383;
    int n = nk >> 7;
    int k = nk & 127;
    const float* W = w ? W2 : W1;
    wt[idx] = f2b(W[((size_t)(l * D + k)) * D + n]);
}

// ---------------- fused MFMA MLP: z2 = relu(relu(z0@W1+b1)@W2+b2), + BN stats ------------
__launch_bounds__(256, 2)
__global__ void mlp_mfma_kernel(const ushort* __restrict__ z0,
                                const ushort* __restrict__ wt1, const float* __restrict__ b1,
                                const ushort* __restrict__ wt2, const float* __restrict__ b2,
                                ushort* __restrict__ out, float* __restrict__ stats) {
    __shared__ ushort As[128 * LDK];
    __shared__ ushort Bs[128 * LDK];
    __shared__ float Ssum[D];
    __shared__ float Ssq[D];

    int tid = threadIdx.x;
    int lane = tid & 63;
    int wave = tid >> 6;
    int rb = blockIdx.x * 128;
    int lrow = lane & 15;
    int lk = lane >> 4;
    int klane = lk * 8;
    int wr0 = wave * 32;

    if (tid < D) { Ssum[tid] = 0.f; Ssq[tid] = 0.f; }

#pragma unroll
    for (int i = 0; i < 8; ++i) {
        int c2 = tid + i * 256;
        int row = c2 >> 4;
        int cc = (c2 & 15) * 8;
        int gr = rb + row;
        bf16x8 v;
#pragma unroll
        for (int e = 0; e < 8; ++e) v[e] = 0;
        if (gr < N_NODES) v = *(const bf16x8*)&z0[(size_t)gr * D + cc];
        *(bf16x8*)&As[row * LDK + cc] = v;
        *(bf16x8*)&Bs[row * LDK + cc] = *(const bf16x8*)&wt1[c2 * 8];
    }
    __syncthreads();

    f32x4 acc[2][8];
#pragma unroll
    for (int a = 0; a < 2; ++a)
#pragma unroll
        for (int b = 0; b < 8; ++b)
#pragma unroll
            for (int r = 0; r < 4; ++r) acc[a][b][r] = 0.f;

#pragma unroll
    for (int ks = 0; ks < 4; ++ks) {
        int k0 = ks * 32 + klane;
        bf16x8 a0 = *(const bf16x8*)&As[(wr0 + lrow) * LDK + k0];
        bf16x8 a1 = *(const bf16x8*)&As[(wr0 + 16 + lrow) * LDK + k0];
#pragma unroll
        for (int ct = 0; ct < 8; ++ct) {
            bf16x8 bb = *(const bf16x8*)&Bs[(ct * 16 + lrow) * LDK + k0];
            acc[0][ct] = __builtin_amdgcn_mfma_f32_16x16x32_bf16(a0, bb, acc[0][ct], 0, 0, 0);
            acc[1][ct] = __builtin_amdgcn_mfma_f32_16x16x32_bf16(a1, bb, acc[1][ct], 0, 0, 0);
        }
    }
    __syncthreads();

#pragma unroll
    for (int rt = 0; rt < 2; ++rt)
#pragma unroll
        for (int ct = 0; ct < 8; ++ct) {
            int col = ct * 16 + lrow;
            float bias = b1[col];
#pragma unroll
            for (int r = 0; r < 4; ++r) {
                int row = wr0 + rt * 16 + lk * 4 + r;
                As[row * LDK + col] = f2b(fmaxf(acc[rt][ct][r] + bias, 0.f));
            }
        }
#pragma unroll
    for (int i = 0; i < 8; ++i) {
        int c2 = tid + i * 256;
        int row = c2 >> 4;
        int cc = (c2 & 15) * 8;
        *(bf16x8*)&Bs[row * LDK + cc] = *(const bf16x8*)&wt2[c2 * 8];
    }
#pragma unroll
    for (int a = 0; a < 2; ++a)
#pragma unroll
        for (int b = 0; b < 8; ++b)
#pragma unroll
            for (int r = 0; r < 4; ++r) acc[a][b][r] = 0.f;
    __syncthreads();

#pragma unroll
    for (int ks = 0; ks < 4; ++ks) {
        int k0 = ks * 32 + klane;
        bf16x8 a0 = *(const bf16x8*)&As[(wr0 + lrow) * LDK + k0];
        bf16x8 a1 = *(const bf16x8*)&As[(wr0 + 16 + lrow) * LDK + k0];
#pragma unroll
        for (int ct = 0; ct < 8; ++ct) {
            bf16x8 bb = *(const bf16x8*)&Bs[(ct * 16 + lrow) * LDK + k0];
            acc[0][ct] = __builtin_amdgcn_mfma_f32_16x16x32_bf16(a0, bb, acc[0][ct], 0, 0, 0);
            acc[1][ct] = __builtin_amdgcn_mfma_f32_16x16x32_bf16(a1, bb, acc[1][ct], 0, 0, 0);
        }
    }
    __syncthreads();

#pragma unroll
    for (int rt = 0; rt < 2; ++rt)
#pragma unroll
        for (int ct = 0; ct < 8; ++ct) {
            int col = ct * 16 + lrow;
            float bias = b2[col];
            float s = 0.f, sq = 0.f;
#pragma unroll
            for (int r = 0; r < 4; ++r) {
                int row = wr0 + rt * 16 + lk * 4 + r;
                float v = fmaxf(acc[rt][ct][r] + bias, 0.f);
                Bs[row * LDK + col] = f2b(v);
                if (rb + row < N_NODES) { s += v; sq += v * v; }
            }
            atomicAdd(&Ssum[col], s);
            atomicAdd(&Ssq[col], sq);
        }
    __syncthreads();

#pragma unroll
    for (int i = 0; i < 8; ++i) {
        int c2 = tid + i * 256;
        int row = c2 >> 4;
        int cc = (c2 & 15) * 8;
        int gr = rb + row;
        if (gr < N_NODES)
            *(bf16x8*)&out[(size_t)gr * D + cc] = *(const bf16x8*)&Bs[row * LDK + cc];
    }
    if (tid < D) {
        atomicAdd(&stats[tid], Ssum[tid]);
        atomicAdd(&stats[D + tid], Ssq[tid]);
    }
}

// ---------------- BN prep: fold stats into per-feature affine A,B ----------------
__global__ void bnprep_kernel(const float* __restrict__ stats, const float* __restrict__ gamma,
                              const float* __restrict__ beta, float* __restrict__ ab) {
    int f = threadIdx.x;
    if (f < D) {
        const float invN = 1.f / (float)N_NODES;
        float mu = stats[f] * invN;
        float var = stats[D + f] * invN - mu * mu;
        float A = gamma[f] * rsqrtf(var + BN_EPS);
        ab[f] = A;
        ab[D + f] = beta[f] - mu * A;
    }
}

// identity affine for layer 0 (standardized x, no BN/relu upstream)
__global__ void init_ab_kernel(float* __restrict__ ab) {
    int f = threadIdx.x;
    if (f < D) { ab[f] = 1.f; ab[D + f] = 0.f; }
}

// ---------------- global_add_pool (batch sorted) with fused final BN+relu ----------------
__global__ void pool_kernel(const ushort* __restrict__ h, const int* __restrict__ batch,
                            const float* __restrict__ ab, float* __restrict__ g) {
    int tid = threadIdx.x;
    int f4 = (tid & 31) * 4;
    int rsub = tid >> 5;
    int r0 = blockIdx.x * POOL_ROWS;
    int rend = r0 + POOL_ROWS;
    if (rend > N_NODES) rend = N_NODES;
    float A0 = ab[f4 + 0], A1 = ab[f4 + 1], A2 = ab[f4 + 2], A3 = ab[f4 + 3];
    float B0 = ab[D + f4 + 0], B1 = ab[D + f4 + 1], B2 = ab[D + f4 + 2], B3 = ab[D + f4 + 3];
    float4 acc = make_float4(0.f, 0.f, 0.f, 0.f);
    int cur = -1;
    for (int r = r0 + rsub; r < rend; r += 8) {
        int b = batch[r];
        if (b != cur) {
            if (cur >= 0) {
                atomicAdd(&g[cur * D + f4 + 0], acc.x);
                atomicAdd(&g[cur * D + f4 + 1], acc.y);
                atomicAdd(&g[cur * D + f4 + 2], acc.z);
                atomicAdd(&g[cur * D + f4 + 3], acc.w);
            }
            acc = make_float4(0.f, 0.f, 0.f, 0.f);
            cur = b;
        }
        ushort4 v = *(const ushort4*)&h[(size_t)r * D + f4];
        acc.x += fmaxf(fmaf(b2f(v.x), A0, B0), 0.f);
        acc.y += fmaxf(fmaf(b2f(v.y), A1, B1), 0.f);
        acc.z += fmaxf(fmaf(b2f(v.z), A2, B2), 0.f);
        acc.w += fmaxf(fmaf(b2f(v.w), A3, B3), 0.f);
    }
    if (cur >= 0) {
        atomicAdd(&g[cur * D + f4 + 0], acc.x);
        atomicAdd(&g[cur * D + f4 + 1], acc.y);
        atomicAdd(&g[cur * D + f4 + 2], acc.z);
        atomicAdd(&g[cur * D + f4 + 3], acc.w);
    }
}

// ---------------- MLP head: 64x128 -> 128 -> 64 -> 10 (fp32) ----------------
__launch_bounds__(512)
__global__ void head_kernel(const float* __restrict__ g,
                            const float* __restrict__ fcw1, const float* __restrict__ fcb1,
                            const float* __restrict__ fcw2, const float* __restrict__ fcb2,
                            const float* __restrict__ fcw3, const float* __restrict__ fcb3,
                            float* __restrict__ out) {
    __shared__ float G[64][128];
    __shared__ float T1[64][128];
    __shared__ float T2[64][64];
    int tid = threadIdx.x;
#pragma unroll
    for (int i = 0; i < 4; ++i) {
        int slot = tid + i * 512;
        ((float4*)G)[slot] = ((const float4*)g)[slot];
    }
    __syncthreads();
#pragma unroll 1
    for (int rep = 0; rep < 16; ++rep) {
        int o = tid + rep * 512;
        int r = o >> 7, c = o & 127;
        float acc = fcb1[c];
        for (int k = 0; k < 128; ++k) acc = fmaf(G[r][k], fcw1[k * 128 + c], acc);
        T1[r][c] = fmaxf(acc, 0.f);
    }
    __syncthreads();
#pragma unroll 1
    for (int rep = 0; rep < 8; ++rep) {
        int o = tid + rep * 512;
        int r = o >> 6, c = o & 63;
        float acc = fcb2[c];
        for (int k = 0; k < 128; ++k) acc = fmaf(T1[r][k], fcw2[k * 64 + c], acc);
        T2[r][c] = fmaxf(acc, 0.f);
    }
    __syncthreads();
    for (int o = tid; o < N_GRAPHS * N_CLASS; o += 512) {
        int r = o / 10, c = o % 10;
        float acc = fcb3[c];
        for (int k = 0; k < 64; ++k) acc = fmaf(T2[r][k], fcw3[k * 10 + c], acc);
        out[o] = acc;
    }
}

extern "C" void kernel_launch(void* const* d_in, const int* in_sizes, int n_in,
                              void* d_out, int out_size, void* d_ws, size_t ws_size,
                              hipStream_t stream) {
    const float* x        = (const float*)d_in[0];
    const int* edge_index = (const int*)d_in[1];
    const int* batch      = (const int*)d_in[2];
    const float* W1       = (const float*)d_in[3];
    const float* b1       = (const float*)d_in[4];
    const float* W2       = (const float*)d_in[5];
    const float* b2       = (const float*)d_in[6];
    const float* gamma    = (const float*)d_in[7];
    const float* beta     = (const float*)d_in[8];
    const float* eps      = (const float*)d_in[9];
    const float* fcw1     = (const float*)d_in[10];
    const float* fcb1     = (const float*)d_in[11];
    const float* fcw2     = (const float*)d_in[12];
    const float* fcb2     = (const float*)d_in[13];
    const float* fcw3     = (const float*)d_in[14];
    const float* fcb3     = (const float*)d_in[15];
    float* out = (float*)d_out;

    char* ws = (char*)d_ws;
    size_t off = 0;
    auto alloc = [&](size_t bytes) -> void* {
        void* p = ws + off;
        off = (off + bytes + 255) & ~(size_t)255;
        return p;
    };
    ushort* hbuf   = (ushort*)alloc((size_t)N_NODES * D * 2);           // 25.6 MB bf16
    ushort* z0buf  = (ushort*)alloc((size_t)N_NODES * D * 2);           // 25.6 MB bf16
    ushort* wtbuf  = (ushort*)alloc((size_t)2 * N_LAYERS * D * D * 2);  // 256 KB
    int2* bpairs   = (int2*)alloc((size_t)N_EDGES * 8);                 // 12.8 MB
    int* colidx    = (int*)alloc((size_t)N_EDGES * 4);                  // 6.4 MB
    int* rowptr    = (int*)alloc((size_t)(N_NODES + 1) * 4);
    int* bucketCount  = (int*)alloc((size_t)NB * 4);
    int* bucketBase   = (int*)alloc((size_t)(NB + 1) * 4);
    int* bucketCursor = (int*)alloc((size_t)NB * 4);
    float* stats   = (float*)alloc(4 * D * 4);   // [sum | sumsq | bnA | bnB]
    float* gpool   = (float*)alloc((size_t)N_GRAPHS * D * 4);
    float* ab      = stats + 2 * D;

    const int* srcArr = edge_index;
    const int* dstArr = edge_index + N_EDGES;

    // ---- bucketed CSR build ----
    zero_u32_kernel<<<1, 256, 0, stream>>>((unsigned int*)bucketCount, NB);
    bucket_count_kernel<<<EDGE_BLOCKS, 256, 0, stream>>>(dstArr, bucketCount);
    bucket_scan_kernel<<<1, 256, 0, stream>>>(bucketCount, bucketBase, bucketCursor);
    bucket_scatter_kernel<<<EDGE_BLOCKS, 256, 0, stream>>>(srcArr, dstArr, bucketCursor, bpairs);
    csr_build_kernel<<<NB, 512, 0, stream>>>(bpairs, bucketBase, rowptr, colidx);

    // ---- StandardScaler (h -> bf16) ----
    zero_u32_kernel<<<1, 256, 0, stream>>>((unsigned int*)stats, 2 * D);
    colstats_kernel<<<(N_NODES + 127) / 128, 256, 0, stream>>>(x, stats);
    standardize_kernel<<<2048, 256, 0, stream>>>(x, stats, hbuf);

    // ---- weight prep + layer-0 identity affine ----
    prep_wt_kernel<<<512, 256, 0, stream>>>(W1, W2, wtbuf);
    init_ab_kernel<<<1, 128, 0, stream>>>(ab);

    // ---- GIN layers (BN+relu of layer l fused into consumers of h_l) ----
    for (int l = 0; l < N_LAYERS; ++l) {
        agg_kernel<<<N_NODES / 8, 256, 0, stream>>>(hbuf, rowptr, colidx, eps, l,
                                                    ab, (l > 0) ? 1 : 0, z0buf);
        zero_u32_kernel<<<1, 256, 0, stream>>>((unsigned int*)stats, 2 * D);
        mlp_mfma_kernel<<<(N_NODES + 127) / 128, 256, 0, stream>>>(
            z0buf, wtbuf + (size_t)l * D * D, b1 + (size_t)l * D,
            wtbuf + (size_t)(N_LAYERS + l) * D * D, b2 + (size_t)l * D, hbuf, stats);
        bnprep_kernel<<<1, 128, 0, stream>>>(stats, gamma + (size_t)l * D,
                                             beta + (size_t)l * D, ab);
    }

    // ---- pool (fused final BN+relu) + head ----
    zero_u32_kernel<<<(N_GRAPHS * D + 255) / 256, 256, 0, stream>>>((unsigned int*)gpool, N_GRAPHS * D);
    pool_kernel<<<(N_NODES + POOL_ROWS - 1) / POOL_ROWS, 256, 0, stream>>>(hbuf, batch, ab, gpool);
    head_kernel<<<1, 512, 0, stream>>>(gpool, fcw1, fcb1, fcw2, fcb2, fcw3, fcb3, out);
}